// Round 1
// 2402.444 us; speedup vs baseline: 1.1754x; 1.1754x over previous
//
#include <hip/hip_runtime.h>

#define T_STEPS 23
#define ORD 256
#define HID 512
#define IN_DIM 256
#define NBATCH 8192
#define SLOPE 0.2f
#define LDH (T_STEPS * HID)   // row stride (floats) of out viewed as [b][t][h]

__device__ __forceinline__ float lrelu(float x) { return x >= 0.f ? x : SLOPE * x; }

// bf16 helpers (round-to-nearest-even, bit tricks; inputs are normal floats)
__device__ __forceinline__ ushort f2bf(float x) {
    unsigned u = __float_as_uint(x);
    u += 0x7fffu + ((u >> 16) & 1u);
    return (ushort)(u >> 16);
}
__device__ __forceinline__ float bf2f(ushort h) { return __uint_as_float((unsigned)h << 16); }

typedef __attribute__((ext_vector_type(8))) short bf16x8;
typedef __attribute__((ext_vector_type(4))) float f32x4;

// ---------------------------------------------------------------------------
// Kernel 1: V[k][i] = (A^k @ Bv)[i], k = 0..22. One block, 256 threads.
__global__ void vchain_kernel(const float* __restrict__ A,
                              const float* __restrict__ Bv,
                              float* __restrict__ V) {
    __shared__ float v[ORD];
    int i = threadIdx.x;
    v[i] = Bv[i];
    __syncthreads();
    for (int k = 0; k < T_STEPS; ++k) {
        V[k * ORD + i] = v[i];
        float a = 0.f;
        const float4* ar = (const float4*)(A + i * ORD);
        const float4* vr = (const float4*)v;
        #pragma unroll 8
        for (int t = 0; t < ORD / 4; ++t) {
            float4 a4 = ar[t];
            float4 v4 = vr[t];
            a += a4.x * v4.x + a4.y * v4.y + a4.z * v4.z + a4.w * v4.w;
        }
        __syncthreads();
        v[i] = a;
        __syncthreads();
    }
}

// ---------------------------------------------------------------------------
// Kernel 2: wtab[k][j] = sum_i W_m[j][i] * V[k][i].  grid (23, 8), 64 threads.
__global__ void wtab_kernel(const float* __restrict__ Wm,
                            const float* __restrict__ V,
                            float* __restrict__ wtab) {
    __shared__ float vs[ORD];
    int k = blockIdx.x;
    int j = blockIdx.y * 64 + threadIdx.x;
    ((float4*)vs)[threadIdx.x] = ((const float4*)(V + k * ORD))[threadIdx.x];
    __syncthreads();
    float a = 0.f;
    const float4* wr = (const float4*)(Wm + j * ORD);
    const float4* vr = (const float4*)vs;
    #pragma unroll 8
    for (int i = 0; i < ORD / 4; ++i) {
        float4 w4 = wr[i];
        float4 v4 = vr[i];
        a += w4.x * v4.x + w4.y * v4.y + w4.z * v4.z + w4.w * v4.w;
    }
    wtab[k * HID + j] = a;
}

// ---------------------------------------------------------------------------
// Kernel 3: u[r] = dot(X[r, :], e_x), r = b*23 + t over 188416 rows.
__global__ void u_kernel(const float* __restrict__ X,
                         const float* __restrict__ ex,
                         float* __restrict__ u) {
    int row = blockIdx.x * 4 + (threadIdx.x >> 6);
    int lane = threadIdx.x & 63;
    const float4* xp = (const float4*)(X + (size_t)row * IN_DIM);
    const float4* ep = (const float4*)ex;
    float4 x4 = xp[lane];
    float4 e4 = ep[lane];
    float acc = x4.x * e4.x + x4.y * e4.y + x4.z * e4.z + x4.w * e4.w;
    #pragma unroll
    for (int off = 32; off; off >>= 1) acc += __shfl_down(acc, off);
    if (lane == 0) u[row] = acc;
}

// ---------------------------------------------------------------------------
// Kernel 4: C[r][n] = sum_k X[r][k] * Wx[k][n].  M=188416, K=256, N=512.
__global__ __launch_bounds__(256) void gemm_xwx(const float* __restrict__ X,
                                                const float* __restrict__ Wx,
                                                float* __restrict__ out) {
    __shared__ float As[16][68];
    __shared__ float Bs[16][68];
    int tid = threadIdx.x;
    int row0 = blockIdx.x * 64;
    int col0 = blockIdx.y * 64;
    int tx = tid & 15, ty = tid >> 4;
    int am = tid >> 2, ak4 = tid & 3;
    float acc[4][4] = {};
    for (int k0 = 0; k0 < 256; k0 += 16) {
        float4 av = *(const float4*)(X + (size_t)(row0 + am) * IN_DIM + k0 + ak4 * 4);
        float4 bv = *(const float4*)(Wx + (size_t)(k0 + ty) * HID + col0 + tx * 4);
        __syncthreads();
        As[ak4 * 4 + 0][am] = av.x;
        As[ak4 * 4 + 1][am] = av.y;
        As[ak4 * 4 + 2][am] = av.z;
        As[ak4 * 4 + 3][am] = av.w;
        *(float4*)&Bs[ty][tx * 4] = bv;
        __syncthreads();
        #pragma unroll
        for (int kk = 0; kk < 16; ++kk) {
            float4 a4 = *(const float4*)&As[kk][ty * 4];
            float4 b4 = *(const float4*)&Bs[kk][tx * 4];
            float a[4] = {a4.x, a4.y, a4.z, a4.w};
            float b[4] = {b4.x, b4.y, b4.z, b4.w};
            #pragma unroll
            for (int i = 0; i < 4; ++i)
                #pragma unroll
                for (int j = 0; j < 4; ++j)
                    acc[i][j] += a[i] * b[j];
        }
    }
    #pragma unroll
    for (int i = 0; i < 4; ++i) {
        float4 v = make_float4(acc[i][0], acc[i][1], acc[i][2], acc[i][3]);
        *(float4*)(out + (size_t)(row0 + ty * 4 + i) * HID + col0 + tx * 4) = v;
    }
}

// ---------------------------------------------------------------------------
// Kernel 5: out[b][t][j] += sum_{s<=t} u[b][s] * wtab[t-s][j].
__global__ __launch_bounds__(512) void memconv_kernel(const float* __restrict__ u,
                                                      const float* __restrict__ wtab,
                                                      float* __restrict__ out) {
    int b = blockIdx.x, j = threadIdx.x;
    __shared__ float us[T_STEPS];
    if (j < T_STEPS) us[j] = u[b * T_STEPS + j];
    float w[T_STEPS];
    #pragma unroll
    for (int k = 0; k < T_STEPS; ++k) w[k] = wtab[k * HID + j];
    __syncthreads();
    float* ob = out + (size_t)b * LDH + j;
    #pragma unroll
    for (int t = 0; t < T_STEPS; ++t) {
        float acc = 0.f;
        #pragma unroll
        for (int s = 0; s <= t; ++s) acc += us[s] * w[t - s];
        ob[t * HID] += acc;
    }
}

// ---------------------------------------------------------------------------
// Kernel 6 (new): pack Wh (512x512 f32, [n][k]) into bf16 hi/lo arrays laid out
// in A-fragment order for mfma_f32_16x16x32_bf16 with the "swapped" GEMM
// D[n][m] = sum_k Wh[n][k] * h[m][k].
// A-frag layout: lane l, elem e -> row n = f*16 + (l&15),
//                k = s*32 + 4*(l>>4) + (e&3) + 16*(e>>2).
// Storage: whp[((f*16 + s)*64 + l)*8 + e]  (1 KB per fragment block, coalesced).
__global__ void whpack_kernel(const float* __restrict__ Wh,
                              ushort* __restrict__ whi,
                              ushort* __restrict__ wlo) {
    int f = blockIdx.x;        // n-fragment 0..31
    int s = blockIdx.y;        // k-step 0..15
    int l = threadIdx.x;       // lane 0..63
    int n = f * 16 + (l & 15);
    int k0 = s * 32 + 4 * (l >> 4);
    float4 a = *(const float4*)(Wh + (size_t)n * HID + k0);
    float4 b = *(const float4*)(Wh + (size_t)n * HID + k0 + 16);
    float v[8] = {a.x, a.y, a.z, a.w, b.x, b.y, b.z, b.w};
    unsigned hp[4], lp[4];
    #pragma unroll
    for (int e2 = 0; e2 < 4; ++e2) {
        ushort h0 = f2bf(v[2 * e2]),     h1 = f2bf(v[2 * e2 + 1]);
        ushort l0 = f2bf(v[2 * e2]     - bf2f(h0));
        ushort l1 = f2bf(v[2 * e2 + 1] - bf2f(h1));
        hp[e2] = (unsigned)h0 | ((unsigned)h1 << 16);
        lp[e2] = (unsigned)l0 | ((unsigned)l1 << 16);
    }
    size_t off = ((size_t)(f * 16 + s) * 64 + l) * 8;
    *(uint4*)(whi + off) = make_uint4(hp[0], hp[1], hp[2], hp[3]);
    *(uint4*)(wlo + off) = make_uint4(lp[0], lp[1], lp[2], lp[3]);
}

// ---------------------------------------------------------------------------
// Kernel 7 (new): fused recurrence, all 23 timesteps, bf16x3 MFMA.
// Block = 32 batch rows x all 512 cols, 512 threads (8 waves), grid 256.
// Per t: out[b][t][n] = lrelu(out[b][t][n] + sum_k h[b][k]*Wh[n][k]),
// computed transposed per-fragment: D[n_local][m_local], A=Wh (prepacked,
// streamed from L2), B=h (LDS, bf16 hi/lo, row-major [32][512], XOR-swizzled).
// h_lds swizzle (ushort units, 8B-granular): off(m,k) = m*512 + (k ^ ((m&15)<<2))

__device__ __forceinline__ bf16x8 ld_frag(const ushort* base, int o1, int o2) {
    ushort4 p = *(const ushort4*)(base + o1);
    ushort4 q = *(const ushort4*)(base + o2);
    bf16x8 r;
    r[0] = (short)p.x; r[1] = (short)p.y; r[2] = (short)p.z; r[3] = (short)p.w;
    r[4] = (short)q.x; r[5] = (short)q.y; r[6] = (short)q.z; r[7] = (short)q.w;
    return r;
}

__device__ __forceinline__ void store_hilo(ushort* hhi, ushort* hlo, int off, float4 v) {
    ushort h0 = f2bf(v.x), h1 = f2bf(v.y), h2 = f2bf(v.z), h3 = f2bf(v.w);
    *(ushort4*)(hhi + off) = make_ushort4(h0, h1, h2, h3);
    ushort l0 = f2bf(v.x - bf2f(h0));
    ushort l1 = f2bf(v.y - bf2f(h1));
    ushort l2 = f2bf(v.z - bf2f(h2));
    ushort l3 = f2bf(v.w - bf2f(h3));
    *(ushort4*)(hlo + off) = make_ushort4(l0, l1, l2, l3);
}

__global__ __launch_bounds__(512) void rec_fused(const ushort* __restrict__ whi,
                                                 const ushort* __restrict__ wlo,
                                                 float* __restrict__ out) {
    __shared__ ushort hhi[32 * 512];
    __shared__ ushort hlo[32 * 512];
    const int tid = threadIdx.x;
    const int w  = tid >> 6;     // wave 0..7, owns n in [w*64, w*64+64)
    const int l  = tid & 63;
    const int lm = l & 15;       // m-within-fragment (B col / D col)
    const int g  = l >> 4;       // lane group 0..3
    const int row0 = blockIdx.x * 32;
    const int xsw = lm << 2;     // LDS swizzle (ushort units)

    // Per-fragment global base: frag (jf, bi): rows row0+bi*16+lm, cols
    // w*64 + jf*16 + 4*g + {0..3}  -> one float4 per fragment.
    float* obase[2];
    obase[0] = out + (size_t)(row0 + lm) * LDH + w * 64 + 4 * g;
    obase[1] = out + (size_t)(row0 + 16 + lm) * LDH + w * 64 + 4 * g;

    // ---- t = 0: h_0 = lrelu(pre_0); write back; seed h LDS ----
    #pragma unroll
    for (int bi = 0; bi < 2; ++bi) {
        #pragma unroll
        for (int jf = 0; jf < 4; ++jf) {
            float4 vv = *(float4*)(obase[bi] + jf * 16);
            vv.x = lrelu(vv.x); vv.y = lrelu(vv.y); vv.z = lrelu(vv.z); vv.w = lrelu(vv.w);
            *(float4*)(obase[bi] + jf * 16) = vv;
            int m  = bi * 16 + lm;
            int nb = w * 64 + jf * 16 + 4 * g;
            store_hilo(hhi, hlo, m * 512 + (nb ^ xsw), vv);
        }
    }

    // Wh-packed per-lane base for this wave (fragments f = w*4 + jf)
    const ushort* wh_l = whi + (size_t)w * 32768 + (size_t)l * 8;
    const ushort* wl_l = wlo + (size_t)w * 32768 + (size_t)l * 8;

    #pragma unroll 1
    for (int t = 1; t < T_STEPS; ++t) {
        __syncthreads();   // h LDS (written last iteration) visible

        f32x4 acc[4][2];
        #pragma unroll
        for (int jf = 0; jf < 4; ++jf)
            #pragma unroll
            for (int bi = 0; bi < 2; ++bi) {
                float4 p = *(float4*)(obase[bi] + t * HID + jf * 16);
                acc[jf][bi][0] = p.x; acc[jf][bi][1] = p.y;
                acc[jf][bi][2] = p.z; acc[jf][bi][3] = p.w;
            }

        #pragma unroll
        for (int s = 0; s < 16; ++s) {
            bf16x8 ah[4], al[4], bh[2], bl[2];
            #pragma unroll
            for (int jf = 0; jf < 4; ++jf) {
                ah[jf] = *(const bf16x8*)(wh_l + jf * 8192 + s * 512);
                al[jf] = *(const bf16x8*)(wl_l + jf * 8192 + s * 512);
            }
            #pragma unroll
            for (int bi = 0; bi < 2; ++bi) {
                int m  = bi * 16 + lm;
                int o1 = m * 512 + ((s * 32 + 4 * g)      ^ xsw);
                int o2 = m * 512 + ((s * 32 + 16 + 4 * g) ^ xsw);
                bh[bi] = ld_frag(hhi, o1, o2);
                bl[bi] = ld_frag(hlo, o1, o2);
            }
            #pragma unroll
            for (int jf = 0; jf < 4; ++jf)
                #pragma unroll
                for (int bi = 0; bi < 2; ++bi) {
                    acc[jf][bi] = __builtin_amdgcn_mfma_f32_16x16x32_bf16(ah[jf], bh[bi], acc[jf][bi], 0, 0, 0);
                    acc[jf][bi] = __builtin_amdgcn_mfma_f32_16x16x32_bf16(ah[jf], bl[bi], acc[jf][bi], 0, 0, 0);
                    acc[jf][bi] = __builtin_amdgcn_mfma_f32_16x16x32_bf16(al[jf], bh[bi], acc[jf][bi], 0, 0, 0);
                }
        }

        __syncthreads();   // everyone done reading h before overwrite

        #pragma unroll
        for (int jf = 0; jf < 4; ++jf)
            #pragma unroll
            for (int bi = 0; bi < 2; ++bi) {
                float4 r;
                r.x = lrelu(acc[jf][bi][0]); r.y = lrelu(acc[jf][bi][1]);
                r.z = lrelu(acc[jf][bi][2]); r.w = lrelu(acc[jf][bi][3]);
                *(float4*)(obase[bi] + t * HID + jf * 16) = r;
                int m  = bi * 16 + lm;
                int nb = w * 64 + jf * 16 + 4 * g;
                store_hilo(hhi, hlo, m * 512 + (nb ^ xsw), r);
            }
    }
}

// ---------------------------------------------------------------------------
extern "C" void kernel_launch(void* const* d_in, const int* in_sizes, int n_in,
                              void* d_out, int out_size, void* d_ws, size_t ws_size,
                              hipStream_t stream) {
    const float* X  = (const float*)d_in[0];  // (8192, 23, 256)
    const float* A  = (const float*)d_in[1];  // (256, 256)
    const float* Bv = (const float*)d_in[2];  // (256, 1)
    const float* Wh = (const float*)d_in[3];  // (512, 512)
    const float* Wm = (const float*)d_in[4];  // (512, 256)
    const float* Wx = (const float*)d_in[5];  // (256, 512)
    const float* ex = (const float*)d_in[6];  // (256, 1)
    float* out = (float*)d_out;               // (8192, 23, 512)

    // workspace: u [188416] f32 | V [23*256] f32 | wtab [23*512] f32 |
    //            whp_hi [512*512] bf16 | whp_lo [512*512] bf16
    float* u    = (float*)d_ws;
    float* V    = u + NBATCH * T_STEPS;
    float* wtab = V + T_STEPS * ORD;
    ushort* whp_hi = (ushort*)(wtab + T_STEPS * HID);
    ushort* whp_lo = whp_hi + HID * HID;

    const int nrows = NBATCH * T_STEPS;  // 188416

    // 1) memory-kernel taps + Wh fragment prepack
    vchain_kernel<<<1, 256, 0, stream>>>(A, Bv, V);
    wtab_kernel<<<dim3(T_STEPS, HID / 64), 64, 0, stream>>>(Wm, V, wtab);
    whpack_kernel<<<dim3(HID / 16, HID / 32), 64, 0, stream>>>(Wh, whp_hi, whp_lo);

    // 2) u = X @ e_x
    u_kernel<<<nrows / 4, 256, 0, stream>>>(X, ex, u);

    // 3) out = X @ W_x (all rows)
    gemm_xwx<<<dim3(nrows / 64, HID / 64), 256, 0, stream>>>(X, Wx, out);

    // 4) out += causal conv of u with wtab
    memconv_kernel<<<NBATCH, HID, 0, stream>>>(u, wtab, out);

    // 5) t = 0..22 fused: h_t = lrelu(pre_t + h_{t-1} @ Wh^T), bf16x3 MFMA,
    //    one persistent block per 32 batch rows (includes the t=0 lrelu).
    rec_fused<<<NBATCH / 32, 512, 0, stream>>>(whp_hi, whp_lo, out);
}